// Round 6
// baseline (648.824 us; speedup 1.0000x reference)
//
#include <hip/hip_runtime.h>
#include <hip/hip_bf16.h>

#define B_DIM 1024
#define L_DIM 50
#define P_DIM 10
#define D_DIM 64
#define V_DIM 100000

typedef __attribute__((ext_vector_type(8))) short bf16x8;
typedef __attribute__((ext_vector_type(4))) float f32x4;

__device__ __forceinline__ unsigned short bf16_rne(float f) {
  unsigned u = __builtin_bit_cast(unsigned, f);
  u += 0x7FFFu + ((u >> 16) & 1u);
  return (unsigned short)(u >> 16);
}

// Kernel 1: x[b][d] = user_emb[uid[b]][d] + low + high + (high*S*(1+S+S^2))*high
// stored as bf16 (RNE) into workspace. One wave per b, one thread per d.
__global__ __launch_bounds__(64) void compute_x_kernel(
    const int* __restrict__ seq, const int* __restrict__ uids,
    const float* __restrict__ item_tab, const float* __restrict__ user_tab,
    unsigned short* __restrict__ xb)
{
  const int b = blockIdx.x;
  const int d = threadIdx.x;
  const int* s = seq + b * L_DIM;
  float sum = 0.f, sumP = 0.f;
#pragma unroll
  for (int l = 0; l < L_DIM; ++l) {
    float e = item_tab[(size_t)s[l] * D_DIM + d];
    sum += e;
    if (l >= L_DIM - P_DIM) sumP += e;
  }
  const float high = sum * (1.0f / L_DIM);
  const float low  = sumP * (1.0f / P_DIM);
  const float S    = sum;
  const float poly = high * S * (1.0f + S + S * S);  // second+third+fourth means
  const float uni  = low + high + poly * high;
  const float x    = user_tab[(size_t)uids[b] * D_DIM + d] + uni;
  xb[b * D_DIM + d] = bf16_rne(x);
}

// Kernel 2: out[1024][100000] = x @ W2^T + b2, bf16 MFMA, fp32 accumulate.
// Block = 4 waves; wave owns 16 rows x 256 cols. No LDS, no barriers.
// Grid = 16 row-tiles x 391 col-tiles (col-tile index = bid>>4 so the 16
// blocks sharing a W2 slice are adjacent in dispatch -> L2/LLC reuse).
__global__ __launch_bounds__(256) void gemm_kernel(
    const unsigned short* __restrict__ xb,
    const float* __restrict__ w2tab,
    const int* __restrict__ idx,
    const float* __restrict__ b2tab,
    float* __restrict__ out)
{
  const int bid  = blockIdx.x;
  const int vt   = bid >> 4;    // 0..390
  const int bt   = bid & 15;    // 0..15
  const int tid  = threadIdx.x;
  const int wave = tid >> 6;
  const int lane = tid & 63;
  const int l15  = lane & 15;
  const int kg   = lane >> 4;   // k-group 0..3

  const int row0 = bt * 64 + wave * 16;
  const int arow = row0 + l15;
  // A fragments: lane holds x[arow][kg*8 + e], e=0..7 (16B contiguous)
  const bf16x8 a0 = *reinterpret_cast<const bf16x8*>(xb + arow * D_DIM + kg * 8);
  const bf16x8 a1 = *reinterpret_cast<const bf16x8*>(xb + arow * D_DIM + 32 + kg * 8);

  const int v0 = vt * 256;
#pragma unroll
  for (int t = 0; t < 16; ++t) {
    const int v  = v0 + t * 16 + l15;
    const int vc = v < V_DIM ? v : V_DIM - 1;
    const int item = idx[vc];
    const float* wrow = w2tab + (size_t)item * D_DIM + kg * 8;
    const float4 w0 = *reinterpret_cast<const float4*>(wrow);
    const float4 w1 = *reinterpret_cast<const float4*>(wrow + 4);
    const float4 w2 = *reinterpret_cast<const float4*>(wrow + 32);
    const float4 w3 = *reinterpret_cast<const float4*>(wrow + 36);
    bf16x8 b0, b1;
    b0[0] = (short)bf16_rne(w0.x); b0[1] = (short)bf16_rne(w0.y);
    b0[2] = (short)bf16_rne(w0.z); b0[3] = (short)bf16_rne(w0.w);
    b0[4] = (short)bf16_rne(w1.x); b0[5] = (short)bf16_rne(w1.y);
    b0[6] = (short)bf16_rne(w1.z); b0[7] = (short)bf16_rne(w1.w);
    b1[0] = (short)bf16_rne(w2.x); b1[1] = (short)bf16_rne(w2.y);
    b1[2] = (short)bf16_rne(w2.z); b1[3] = (short)bf16_rne(w2.w);
    b1[4] = (short)bf16_rne(w3.x); b1[5] = (short)bf16_rne(w3.y);
    b1[6] = (short)bf16_rne(w3.z); b1[7] = (short)bf16_rne(w3.w);

    const float bias = b2tab[item];
    f32x4 c = {bias, bias, bias, bias};  // C/D: col = lane&15, row = kg*4 + reg
    c = __builtin_amdgcn_mfma_f32_16x16x32_bf16(a0, b0, c, 0, 0, 0);
    c = __builtin_amdgcn_mfma_f32_16x16x32_bf16(a1, b1, c, 0, 0, 0);

    if (v < V_DIM) {
      float* op = out + (size_t)(row0 + kg * 4) * V_DIM + v;
#pragma unroll
      for (int j = 0; j < 4; ++j)
        __builtin_nontemporal_store(c[j], op + (size_t)j * V_DIM);
    }
  }
}

extern "C" void kernel_launch(void* const* d_in, const int* in_sizes, int n_in,
                              void* d_out, int out_size, void* d_ws, size_t ws_size,
                              hipStream_t stream) {
  const int*   seq      = (const int*)d_in[0];
  const int*   uids     = (const int*)d_in[1];
  const int*   idx      = (const int*)d_in[2];
  const float* item_tab = (const float*)d_in[3];
  const float* user_tab = (const float*)d_in[4];
  const float* w2tab    = (const float*)d_in[5];
  const float* b2tab    = (const float*)d_in[6];
  float* out = (float*)d_out;
  unsigned short* xb = (unsigned short*)d_ws;  // 1024*64*2 = 128 KB

  compute_x_kernel<<<B_DIM, 64, 0, stream>>>(seq, uids, item_tab, user_tab, xb);

  const int vtiles = (V_DIM + 255) / 256;  // 391
  gemm_kernel<<<vtiles * 16, 256, 0, stream>>>(xb, w2tab, idx, b2tab, out);
}